// Round 2
// baseline (360.524 us; speedup 1.0000x reference)
//
#include <hip/hip_runtime.h>

// CrossAttention: B=2, C=256, H=W=64 (N=4096), NH=4 heads of hd=64, G=32 groups.
// Pipeline (all bf16 MFMA internally, fp32 I/O):
//   wcvt:    weights fp32 -> bf16
//   gnorm:   GroupNorm(input)->nqT[b][n][c], GroupNorm(c)->nkvT (transposed bf16)
//   proj:    QT[b][n][256] = (nqT . wq^T) * 1/16 ;  KVT[b][n][512] = nkvT . wkv^T
//   attn:    flash-style per (b,h,qblock=64): S=Q K^T (scale pre-folded), online
//            softmax, O += P V ; writes Ot[b][n][256]
//            NOTE kv split is PER-HEAD: K ch = [128h,128h+64), V ch = [128h+64,128h+128)
//   outproj: out[b][o][n] = wout . Ot^T + bias + input   (fp32 out)

typedef __attribute__((ext_vector_type(8))) short short8;   // 8 x bf16 bits
typedef __attribute__((ext_vector_type(4))) float f32x4;

__device__ __forceinline__ unsigned short f2bf(float x) {
    unsigned int u = __builtin_bit_cast(unsigned int, x);
    u += 0x7FFFu + ((u >> 16) & 1u);   // round-to-nearest-even
    return (unsigned short)(u >> 16);
}

__device__ __forceinline__ short8 ld8(const unsigned short* p) {
    return *reinterpret_cast<const short8*>(p);
}

#define MFMA(a, b, c) __builtin_amdgcn_mfma_f32_16x16x32_bf16((a), (b), (c), 0, 0, 0)

// ---------------------------------------------------------------- weights cvt
__global__ __launch_bounds__(256) void wcvt(const float* __restrict__ wq,
                                            const float* __restrict__ wkv,
                                            const float* __restrict__ wo,
                                            unsigned short* __restrict__ dst) {
    int i = blockIdx.x * 256 + threadIdx.x;   // 262144 total
    float v;
    if (i < 65536)       v = wq[i];
    else if (i < 196608) v = wkv[i - 65536];
    else                 v = wo[i - 196608];
    dst[i] = f2bf(v);
}

// ---------------------------------------------------------------- group norm
// grid.x = 128: [tensor(2)][b(2)][group(32)]; writes transposed bf16 [b][n][256]
__global__ __launch_bounds__(256) void gnorm(const float* __restrict__ x0,
                                             const float* __restrict__ x1,
                                             unsigned short* __restrict__ d0,
                                             unsigned short* __restrict__ d1,
                                             const float* __restrict__ gamma,
                                             const float* __restrict__ beta) {
    int bid = blockIdx.x;
    const float* x = (bid & 64) ? x1 : x0;
    unsigned short* dst = (bid & 64) ? d1 : d0;
    int b = (bid >> 5) & 1, g = bid & 31;
    const float* base = x + (size_t)(b * 256 + g * 8) * 4096;  // 8 ch x 4096, contiguous
    int tid = threadIdx.x, lane = tid & 63, w = tid >> 6;

    float s = 0.f, s2 = 0.f;
    const float4* b4 = (const float4*)base;          // 8192 float4
    for (int i = tid; i < 8192; i += 256) {
        float4 v = b4[i];
        s  += v.x + v.y + v.z + v.w;
        s2 += v.x * v.x + v.y * v.y + v.z * v.z + v.w * v.w;
    }
    #pragma unroll
    for (int off = 32; off; off >>= 1) {
        s  += __shfl_down(s, off);
        s2 += __shfl_down(s2, off);
    }
    __shared__ float red[8];
    __shared__ float stat[2];
    if (lane == 0) { red[w] = s; red[4 + w] = s2; }
    __syncthreads();
    if (tid == 0) {
        float S = red[0] + red[1] + red[2] + red[3];
        float S2 = red[4] + red[5] + red[6] + red[7];
        float mean = S * (1.f / 32768.f);
        float var = S2 * (1.f / 32768.f) - mean * mean;
        stat[0] = mean;
        stat[1] = rsqrtf(var + 1e-5f);
    }
    __syncthreads();
    float mean = stat[0], inv = stat[1];

    float a[8], c0[8];
    #pragma unroll
    for (int cl = 0; cl < 8; cl++) {
        float gm = gamma[g * 8 + cl], bt = beta[g * 8 + cl];
        a[cl]  = gm * inv;
        c0[cl] = bt - mean * gm * inv;
    }
    for (int n = tid; n < 4096; n += 256) {
        unsigned short o[8];
        #pragma unroll
        for (int cl = 0; cl < 8; cl++) {
            float v = base[cl * 4096 + n];            // coalesced per cl
            o[cl] = f2bf(v * a[cl] + c0[cl]);
        }
        *(uint4*)&dst[((size_t)(b * 4096 + n)) * 256 + g * 8] = *(const uint4*)o;
    }
}

// ---------------------------------------------------------------- projections
// OT[b][n][MOUT] = scale * (XT[b][n][:] . W[o][:])   all operands row-major in k
template <int MOUT>
__global__ __launch_bounds__(256) void proj(const unsigned short* __restrict__ XT,
                                            const unsigned short* __restrict__ W,
                                            unsigned short* __restrict__ OT,
                                            float scale) {
    int bb = blockIdx.z;
    int n0 = blockIdx.x * 128;
    int o0 = blockIdx.y * 64;
    int w = threadIdx.x >> 6, lane = threadIdx.x & 63;
    int m16 = lane & 15, g = lane >> 4;
    const unsigned short* Xb = XT + (size_t)bb * 4096 * 256;
    f32x4 acc[2][4] = {};
    int rowA = n0 + w * 32 + m16;
    #pragma unroll
    for (int k0 = 0; k0 < 256; k0 += 32) {
        short8 a0 = ld8(Xb + (size_t)rowA * 256 + k0 + g * 8);
        short8 a1 = ld8(Xb + (size_t)(rowA + 16) * 256 + k0 + g * 8);
        #pragma unroll
        for (int ct = 0; ct < 4; ct++) {
            short8 bf = ld8(W + (size_t)(o0 + ct * 16 + m16) * 256 + k0 + g * 8);
            acc[0][ct] = MFMA(a0, bf, acc[0][ct]);
            acc[1][ct] = MFMA(a1, bf, acc[1][ct]);
        }
    }
    unsigned short* Ob = OT + (size_t)bb * 4096 * MOUT;
    #pragma unroll
    for (int mt = 0; mt < 2; mt++)
        #pragma unroll
        for (int ct = 0; ct < 4; ct++)
            #pragma unroll
            for (int r = 0; r < 4; r++) {
                int n = n0 + w * 32 + mt * 16 + g * 4 + r;
                int o = o0 + ct * 16 + m16;
                Ob[(size_t)n * MOUT + o] = f2bf(acc[mt][ct][r] * scale);
            }
}

// ---------------------------------------------------------------- attention
// grid (64 qblocks, 4 heads, 2 batch); 4 waves x 16 q-rows; K-tile = 64
// Per-head KV split: K = KVT[n][128h .. 128h+64), V = KVT[n][128h+64 .. 128h+128)
__global__ __launch_bounds__(256) void attn(const unsigned short* __restrict__ QT,
                                            const unsigned short* __restrict__ KVT,
                                            unsigned short* __restrict__ OT) {
    __shared__ unsigned short vt[64 * 72];        // V-tile transposed [dd][kk]
    __shared__ unsigned short pl[4 * 16 * 72];    // per-wave P strips [r][kk]
    int qb = blockIdx.x, h = blockIdx.y, bb = blockIdx.z;
    int w = threadIdx.x >> 6, lane = threadIdx.x & 63;
    int m16 = lane & 15, g = lane >> 4;
    const unsigned short* Qb = QT + (size_t)bb * 4096 * 256;
    const unsigned short* Kb = KVT + (size_t)bb * 4096 * 512;

    int qrow = qb * 64 + w * 16 + m16;
    short8 aq0 = ld8(Qb + (size_t)qrow * 256 + h * 64 + g * 8);       // scale pre-folded
    short8 aq1 = ld8(Qb + (size_t)qrow * 256 + h * 64 + 32 + g * 8);

    f32x4 o_acc[4] = {};
    float m_i[4], l_i[4];
    #pragma unroll
    for (int r = 0; r < 4; r++) { m_i[r] = -1e30f; l_i[r] = 0.f; }
    unsigned short* myP = pl + w * 16 * 72;

    int vkkp = threadIdx.x >> 3;            // 0..31 (kk pair)
    int vdd0 = (threadIdx.x & 7) * 8;       // 0..56

    for (int kt = 0; kt < 64; kt++) {
        __syncthreads();   // previous iter's vt reads done
        {   // stage V-tile transposed: Vt[dd][kk] = KVT[kt*64+kk][128h+64+dd]
            const unsigned short* vsrc =
                Kb + (size_t)(kt * 64 + vkkp * 2) * 512 + h * 128 + 64 + vdd0;
            uint4 r0 = *(const uint4*)vsrc;
            uint4 r1 = *(const uint4*)(vsrc + 512);
            const unsigned short* s0 = (const unsigned short*)&r0;
            const unsigned short* s1 = (const unsigned short*)&r1;
            #pragma unroll
            for (int i = 0; i < 8; i++) {
                unsigned int pk = (unsigned int)s0[i] | ((unsigned int)s1[i] << 16);
                *(unsigned int*)&vt[(vdd0 + i) * 72 + vkkp * 2] = pk;
            }
        }
        __syncthreads();

        // S = Q K^T for this wave's 16 q-rows x 64 kk
        f32x4 s[4];
        #pragma unroll
        for (int ct = 0; ct < 4; ct++) {
            const unsigned short* kp = Kb + (size_t)(kt * 64 + ct * 16 + m16) * 512 + h * 128;
            short8 bk0 = ld8(kp + g * 8);
            short8 bk1 = ld8(kp + 32 + g * 8);
            f32x4 z = {};
            z = MFMA(aq0, bk0, z);
            s[ct] = MFMA(aq1, bk1, z);
        }

        // online softmax: row = g*4+r lives across the 16-lane group (cols = m16)
        float mloc[4];
        #pragma unroll
        for (int r = 0; r < 4; r++)
            mloc[r] = fmaxf(fmaxf(s[0][r], s[1][r]), fmaxf(s[2][r], s[3][r]));
        #pragma unroll
        for (int off = 1; off < 16; off <<= 1)
            #pragma unroll
            for (int r = 0; r < 4; r++)
                mloc[r] = fmaxf(mloc[r], __shfl_xor(mloc[r], off));
        float alpha[4], ls[4];
        #pragma unroll
        for (int r = 0; r < 4; r++) {
            float mn = fmaxf(m_i[r], mloc[r]);
            alpha[r] = __expf(m_i[r] - mn);
            m_i[r] = mn;
            ls[r] = 0.f;
        }
        #pragma unroll
        for (int ct = 0; ct < 4; ct++)
            #pragma unroll
            for (int r = 0; r < 4; r++) {
                float p = __expf(s[ct][r] - m_i[r]);
                s[ct][r] = p;
                ls[r] += p;
            }
        #pragma unroll
        for (int off = 1; off < 16; off <<= 1)
            #pragma unroll
            for (int r = 0; r < 4; r++)
                ls[r] += __shfl_xor(ls[r], off);
        #pragma unroll
        for (int r = 0; r < 4; r++) l_i[r] = l_i[r] * alpha[r] + ls[r];
        #pragma unroll
        for (int dt = 0; dt < 4; dt++)
            #pragma unroll
            for (int r = 0; r < 4; r++) o_acc[dt][r] *= alpha[r];

        // P: C-layout -> LDS strip -> A-layout (wave-private, no barrier)
        #pragma unroll
        for (int ct = 0; ct < 4; ct++)
            #pragma unroll
            for (int r = 0; r < 4; r++)
                myP[(g * 4 + r) * 72 + ct * 16 + m16] = f2bf(s[ct][r]);
        short8 ap0 = ld8(myP + m16 * 72 + g * 8);
        short8 ap1 = ld8(myP + m16 * 72 + 32 + g * 8);

        // O += P V
        #pragma unroll
        for (int dt = 0; dt < 4; dt++) {
            short8 bv0 = ld8(vt + (dt * 16 + m16) * 72 + g * 8);
            short8 bv1 = ld8(vt + (dt * 16 + m16) * 72 + 32 + g * 8);
            o_acc[dt] = MFMA(ap0, bv0, o_acc[dt]);
            o_acc[dt] = MFMA(ap1, bv1, o_acc[dt]);
        }
    }

    unsigned short* Ob = OT + (size_t)bb * 4096 * 256;
    float invl[4];
    #pragma unroll
    for (int r = 0; r < 4; r++) invl[r] = 1.f / l_i[r];
    #pragma unroll
    for (int dt = 0; dt < 4; dt++)
        #pragma unroll
        for (int r = 0; r < 4; r++) {
            int n = qb * 64 + w * 16 + g * 4 + r;
            Ob[(size_t)n * 256 + h * 64 + dt * 16 + m16] = f2bf(o_acc[dt][r] * invl[r]);
        }
}

// ---------------------------------------------------------------- out proj
// out[b][o][n] = wout[o][:] . Ot[b][n][:] + bias[o] + input[b][o][n]
__global__ __launch_bounds__(256) void outproj(const unsigned short* __restrict__ Ot,
                                               const unsigned short* __restrict__ Wo,
                                               const float* __restrict__ bias,
                                               const float* __restrict__ resid,
                                               float* __restrict__ out) {
    int bb = blockIdx.z;
    int n0 = blockIdx.x * 128;
    int o0 = blockIdx.y * 64;
    int w = threadIdx.x >> 6, lane = threadIdx.x & 63;
    int m16 = lane & 15, g = lane >> 4;
    const unsigned short* Ob = Ot + (size_t)bb * 4096 * 256;
    int orow = o0 + w * 16 + m16;
    f32x4 acc[8] = {};
    #pragma unroll
    for (int k0 = 0; k0 < 256; k0 += 32) {
        short8 a = ld8(Wo + (size_t)orow * 256 + k0 + g * 8);
        #pragma unroll
        for (int ct = 0; ct < 8; ct++) {
            short8 bf = ld8(Ob + (size_t)(n0 + ct * 16 + m16) * 256 + k0 + g * 8);
            acc[ct] = MFMA(a, bf, acc[ct]);
        }
    }
    float biasr[4];
    #pragma unroll
    for (int r = 0; r < 4; r++) biasr[r] = bias[o0 + w * 16 + g * 4 + r];
    #pragma unroll
    for (int ct = 0; ct < 8; ct++)
        #pragma unroll
        for (int r = 0; r < 4; r++) {
            int o = o0 + w * 16 + g * 4 + r;
            int n = n0 + ct * 16 + m16;
            size_t idx = ((size_t)bb * 256 + o) * 4096 + n;
            out[idx] = acc[ct][r] + biasr[r] + resid[idx];
        }
}

// ---------------------------------------------------------------- launch
extern "C" void kernel_launch(void* const* d_in, const int* in_sizes, int n_in,
                              void* d_out, int out_size, void* d_ws, size_t ws_size,
                              hipStream_t stream) {
    const float* input  = (const float*)d_in[0];
    const float* cctx   = (const float*)d_in[1];
    const float* gn_w   = (const float*)d_in[2];
    const float* gn_b   = (const float*)d_in[3];
    const float* wq     = (const float*)d_in[4];
    const float* wkv    = (const float*)d_in[5];
    const float* wout_w = (const float*)d_in[6];
    const float* wout_b = (const float*)d_in[7];
    float* out = (float*)d_out;

    unsigned short* ws = (unsigned short*)d_ws;
    unsigned short* wq_bf   = ws;                   //  65536 ush
    unsigned short* wkv_bf  = ws + 65536;           // 131072
    unsigned short* wout_bf = ws + 196608;          //  65536
    unsigned short* nqT  = ws + 262144;             // 2*4096*256
    unsigned short* nkvT = nqT + 2097152;
    unsigned short* QT   = nkvT + 2097152;
    unsigned short* KVT  = QT + 2097152;            // 2*4096*512
    unsigned short* OtT  = KVT + 4194304;           // total ~24.5 MiB

    wcvt<<<1024, 256, 0, stream>>>(wq, wkv, wout_w, ws);
    gnorm<<<128, 256, 0, stream>>>(input, cctx, nqT, nkvT, gn_w, gn_b);
    proj<256><<<dim3(32, 4, 2), 256, 0, stream>>>(nqT, wq_bf, QT, 0.0625f);  // 1/sqrt(256)
    proj<512><<<dim3(32, 8, 2), 256, 0, stream>>>(nkvT, wkv_bf, KVT, 1.0f);
    attn<<<dim3(64, 4, 2), 256, 0, stream>>>(QT, KVT, OtT);
    outproj<<<dim3(32, 4, 2), 256, 0, stream>>>(OtT, wout_bf, wout_b, input, out);
}